// Round 1
// baseline (120.705 us; speedup 1.0000x reference)
//
#include <hip/hip_runtime.h>

#define N_NODES 8192
#define E_EDGES 262144
#define EMBDSZ  64
#define NIN     16
#define K_STEPS 4

#define HASH_BITS 20
#define HASH_SIZE (1u << HASH_BITS)
#define HASH_MASK (HASH_SIZE - 1u)
#define EMPTY_KEY 0xFFFFFFFFu

__device__ __forceinline__ unsigned hash_key(unsigned key) {
    return (key * 2654435761u) >> (32 - HASH_BITS);
}

// x0[n][j] = sum_k nf[n][k] * Emb[k][j]
__global__ void embed_kernel(const float* __restrict__ nf,
                             const float* __restrict__ emb,
                             float* __restrict__ x0) {
    __shared__ float semb[EMBDSZ * NIN];
    int tid = threadIdx.x;
    for (int i = tid; i < EMBDSZ * NIN; i += blockDim.x) semb[i] = emb[i];
    __syncthreads();
    int gid = blockIdx.x * blockDim.x + tid;
    int n = gid >> 4, j = gid & 15;
    if (n < N_NODES) {
        float acc = 0.f;
        #pragma unroll
        for (int k = 0; k < EMBDSZ; ++k) acc += nf[n * EMBDSZ + k] * semb[k * NIN + j];
        x0[n * NIN + j] = acc;
    }
}

// Claim a hash slot per (r,c) key; track max edge index (last write wins).
__global__ void dedup_insert(const int* __restrict__ ei,
                             unsigned* __restrict__ hkey,
                             unsigned* __restrict__ hval) {
    int e = blockIdx.x * blockDim.x + threadIdx.x;
    if (e >= E_EDGES) return;
    unsigned r = (unsigned)ei[e];
    unsigned c = (unsigned)ei[E_EDGES + e];
    unsigned key = (r << 13) | c;
    unsigned h = hash_key(key);
    while (true) {
        unsigned prev = atomicCAS(&hkey[h], EMPTY_KEY, key);
        if (prev == EMPTY_KEY || prev == key) {
            atomicMax(&hval[h], (unsigned)e);
            break;
        }
        h = (h + 1) & HASH_MASK;
    }
}

__device__ __forceinline__ unsigned hash_lookup(const unsigned* __restrict__ hkey,
                                                unsigned key) {
    unsigned h = hash_key(key);
    while (hkey[h] != key) h = (h + 1) & HASH_MASK;
    return h;
}

// Count surviving edges per destination row.
__global__ void dedup_count(const int* __restrict__ ei,
                            const unsigned* __restrict__ hkey,
                            const unsigned* __restrict__ hval,
                            unsigned* __restrict__ counts) {
    int e = blockIdx.x * blockDim.x + threadIdx.x;
    if (e >= E_EDGES) return;
    unsigned r = (unsigned)ei[e];
    unsigned c = (unsigned)ei[E_EDGES + e];
    unsigned key = (r << 13) | c;
    unsigned h = hash_lookup(hkey, key);
    if (hval[h] == (unsigned)e) atomicAdd(&counts[r], 1u);
}

// Exclusive scan of 8192 row counts -> offsets[8193] and cursor copy.
__global__ void scan_kernel(const unsigned* __restrict__ counts,
                            unsigned* __restrict__ offsets,
                            unsigned* __restrict__ cursor) {
    __shared__ unsigned tot[256];
    __shared__ unsigned pre[256];
    int t = threadIdx.x;
    unsigned local[32];
    unsigned s = 0;
    #pragma unroll
    for (int i = 0; i < 32; ++i) { local[i] = counts[t * 32 + i]; s += local[i]; }
    tot[t] = s;
    __syncthreads();
    if (t == 0) {
        unsigned run = 0;
        for (int i = 0; i < 256; ++i) { pre[i] = run; run += tot[i]; }
    }
    __syncthreads();
    unsigned run = pre[t];
    #pragma unroll
    for (int i = 0; i < 32; ++i) {
        unsigned r = t * 32 + i;
        offsets[r] = run;
        cursor[r]  = run;
        run += local[i];
    }
    if (t == 255) offsets[N_NODES] = run;
}

// Scatter surviving edges into CSR (col + weight arrays).
__global__ void dedup_fill(const int* __restrict__ ei,
                           const float* __restrict__ ew,
                           const unsigned* __restrict__ hkey,
                           const unsigned* __restrict__ hval,
                           unsigned* __restrict__ cursor,
                           unsigned* __restrict__ csr_col,
                           float* __restrict__ csr_w) {
    int e = blockIdx.x * blockDim.x + threadIdx.x;
    if (e >= E_EDGES) return;
    unsigned r = (unsigned)ei[e];
    unsigned c = (unsigned)ei[E_EDGES + e];
    unsigned key = (r << 13) | c;
    unsigned h = hash_lookup(hkey, key);
    if (hval[h] == (unsigned)e) {
        unsigned p = atomicAdd(&cursor[r], 1u);
        csr_col[p] = c;
        csr_w[p]   = ew[e];
    }
}

// One wave per row: lanes = 4 edge-slots x 16 feature-lanes.
__global__ void spmm_kernel(const unsigned* __restrict__ offsets,
                            const unsigned* __restrict__ csr_col,
                            const float* __restrict__ csr_w,
                            const float* __restrict__ hin,
                            float* __restrict__ hout) {
    int row  = (blockIdx.x * blockDim.x + threadIdx.x) >> 6;
    int lane = threadIdx.x & 63;
    if (row >= N_NODES) return;
    unsigned start = offsets[row], end = offsets[row + 1];
    int sub = lane >> 4, j = lane & 15;
    float acc = 0.f;
    for (unsigned i = start + sub; i < end; i += 4) {
        unsigned c = csr_col[i];
        float w   = csr_w[i];
        acc += w * hin[c * NIN + j];
    }
    acc += __shfl_xor(acc, 16);
    acc += __shfl_xor(acc, 32);
    if (sub == 0) hout[row * NIN + j] = acc;
}

extern "C" void kernel_launch(void* const* d_in, const int* in_sizes, int n_in,
                              void* d_out, int out_size, void* d_ws, size_t ws_size,
                              hipStream_t stream) {
    (void)in_sizes; (void)n_in; (void)out_size; (void)ws_size;
    const float* nf  = (const float*)d_in[0];
    const int*   ei  = (const int*)d_in[1];
    const float* ew  = (const float*)d_in[2];
    const float* emb = (const float*)d_in[3];
    float* out = (float*)d_out;

    char* ws = (char*)d_ws;
    size_t off = 0;
    auto alloc = [&](size_t bytes) {
        void* p = ws + off;
        off += (bytes + 255) & ~(size_t)255;
        return p;
    };
    float*    x0      = (float*)   alloc((size_t)N_NODES * NIN * 4);
    unsigned* hkey    = (unsigned*)alloc((size_t)HASH_SIZE * 4);
    unsigned* hval    = (unsigned*)alloc((size_t)HASH_SIZE * 4);
    unsigned* counts  = (unsigned*)alloc((size_t)N_NODES * 4);
    unsigned* offsets = (unsigned*)alloc((size_t)(N_NODES + 1) * 4);
    unsigned* cursor  = (unsigned*)alloc((size_t)N_NODES * 4);
    unsigned* csr_col = (unsigned*)alloc((size_t)E_EDGES * 4);
    float*    csr_w   = (float*)   alloc((size_t)E_EDGES * 4);

    hipMemsetAsync(hkey,   0xFF, (size_t)HASH_SIZE * 4, stream);
    hipMemsetAsync(hval,   0x00, (size_t)HASH_SIZE * 4, stream);
    hipMemsetAsync(counts, 0x00, (size_t)N_NODES * 4, stream);

    embed_kernel<<<(N_NODES * NIN) / 256, 256, 0, stream>>>(nf, emb, x0);
    dedup_insert<<<E_EDGES / 256, 256, 0, stream>>>(ei, hkey, hval);
    dedup_count<<<E_EDGES / 256, 256, 0, stream>>>(ei, hkey, hval, counts);
    scan_kernel<<<1, 256, 0, stream>>>(counts, offsets, cursor);
    dedup_fill<<<E_EDGES / 256, 256, 0, stream>>>(ei, ew, hkey, hval, cursor, csr_col, csr_w);

    const float* hin = x0;
    for (int k = 0; k < K_STEPS; ++k) {
        float* hout = out + (size_t)k * N_NODES * NIN;
        spmm_kernel<<<N_NODES / 4, 256, 0, stream>>>(offsets, csr_col, csr_w, hin, hout);
        hin = hout;
    }
}